// Round 7
// baseline (593.013 us; speedup 1.0000x reference)
//
#include <hip/hip_runtime.h>

// Problem constants
#define NPOS   524288         // 8*16*64*64
#define KCODES 512
#define CDIM   64
#define THW    65536          // 16*64*64
#define NTHR   256            // 4 waves; one position per thread

// out layout (float32): [0, 33554432) quantized BCTHW; [33554432] loss; [33554433, +524288) indices
#define QOUT_N   33554432L
#define LOSS_OFF 33554432L
#define IDX_OFF  33554433L

// ws layout: byte 0: double loss acc; byte 256: float ee[512]; byte 4096: float etg[64][64][8]
//   etg[qg][c][k] = emb[qg*8+k][c]

// ---------- prep: ee[q] (numpy pairwise-8) and grouped-transposed codebook ----------
extern "C" __global__ void vq_prep(const float* __restrict__ emb,
                                   float* __restrict__ ee, float* __restrict__ etg) {
    int q = threadIdx.x;               // 512 threads
    const float* er = emb + q * 64;
    float r[8];
    #pragma unroll
    for (int j = 0; j < 8; ++j) { float v = er[j]; r[j] = __fmul_rn(v, v); }
    #pragma unroll
    for (int t = 1; t < 8; ++t)
        #pragma unroll
        for (int j = 0; j < 8; ++j) { float v = er[t * 8 + j]; r[j] = __fadd_rn(r[j], __fmul_rn(v, v)); }
    float s0 = __fadd_rn(__fadd_rn(r[0], r[1]), __fadd_rn(r[2], r[3]));
    float s1 = __fadd_rn(__fadd_rn(r[4], r[5]), __fadd_rn(r[6], r[7]));
    ee[q] = __fadd_rn(s0, s1);
    int qg = q >> 3, k = q & 7;
    #pragma unroll
    for (int c = 0; c < 64; ++c) etg[(qg * 64 + c) * 8 + k] = er[c];
}

// ---- X-macros over the 64 channels (named scalars -> guaranteed VGPR residency)
#define R63(M) M(1)M(2)M(3)M(4)M(5)M(6)M(7)M(8)M(9)M(10)M(11)M(12)M(13)M(14)M(15)\
M(16)M(17)M(18)M(19)M(20)M(21)M(22)M(23)M(24)M(25)M(26)M(27)M(28)M(29)M(30)M(31)\
M(32)M(33)M(34)M(35)M(36)M(37)M(38)M(39)M(40)M(41)M(42)M(43)M(44)M(45)M(46)M(47)\
M(48)M(49)M(50)M(51)M(52)M(53)M(54)M(55)M(56)M(57)M(58)M(59)M(60)M(61)M(62)M(63)
#define R64(M) M(0)R63(M)

// ---------- main: one position per thread, codebook via scalar path ----------
extern "C" __global__ __launch_bounds__(NTHR, 4)
void vq_main(const float* __restrict__ x, const float* __restrict__ emb,
             float* __restrict__ out, double* __restrict__ lossws,
             const float* __restrict__ eeg, const float* __restrict__ etg) {
    const int tid = threadIdx.x;
    const int blk = blockIdx.x;
    const int b   = blk >> 8;                    // 256 blocks per batch element
    const int r   = ((blk & 255) << 8) + tid;    // position within [0, THW)
    const long n  = (long)blk * NTHR + tid;      // global position index

    // ---- load this position's 64 channels into named registers (coalesced)
    const float* xp = x + (long)b * CDIM * THW + r;
#define DECL_A(c) float A##c = xp[(long)(c) * THW];
    R64(DECL_A)
#undef DECL_A

    // ---- ff = sum_c a^2, numpy pairwise-8 order
    float rr0 = __fmul_rn(A0, A0), rr1 = __fmul_rn(A1, A1);
    float rr2 = __fmul_rn(A2, A2), rr3 = __fmul_rn(A3, A3);
    float rr4 = __fmul_rn(A4, A4), rr5 = __fmul_rn(A5, A5);
    float rr6 = __fmul_rn(A6, A6), rr7 = __fmul_rn(A7, A7);
#define FFT(e0,e1,e2,e3,e4,e5,e6,e7) \
    rr0 = __fadd_rn(rr0, __fmul_rn(A##e0, A##e0)); \
    rr1 = __fadd_rn(rr1, __fmul_rn(A##e1, A##e1)); \
    rr2 = __fadd_rn(rr2, __fmul_rn(A##e2, A##e2)); \
    rr3 = __fadd_rn(rr3, __fmul_rn(A##e3, A##e3)); \
    rr4 = __fadd_rn(rr4, __fmul_rn(A##e4, A##e4)); \
    rr5 = __fadd_rn(rr5, __fmul_rn(A##e5, A##e5)); \
    rr6 = __fadd_rn(rr6, __fmul_rn(A##e6, A##e6)); \
    rr7 = __fadd_rn(rr7, __fmul_rn(A##e7, A##e7));
    FFT(8,9,10,11,12,13,14,15)
    FFT(16,17,18,19,20,21,22,23)
    FFT(24,25,26,27,28,29,30,31)
    FFT(32,33,34,35,36,37,38,39)
    FFT(40,41,42,43,44,45,46,47)
    FFT(48,49,50,51,52,53,54,55)
    FFT(56,57,58,59,60,61,62,63)
#undef FFT
    const float ffv = __fadd_rn(
        __fadd_rn(__fadd_rn(rr0, rr1), __fadd_rn(rr2, rr3)),
        __fadd_rn(__fadd_rn(rr4, rr5), __fadd_rn(rr6, rr7)));

    // ---- argmin over all 512 codes, 8 codes per group, e via scalar loads
    float dmin = 1e30f; int kmin = 0;
    #pragma unroll 1
    for (int qg = 0; qg < 64; ++qg) {
        const float* eq  = etg + qg * 512;       // uniform -> s_load
        const float* ees = eeg + qg * 8;         // uniform -> s_load
        // c = 0: chain starts with multiply (bit-safe vs fma-into-zero: only
        // sign-of-zero can differ, which cannot change a strict-< argmin)
        float acc0 = __fmul_rn(A0, eq[0]), acc1 = __fmul_rn(A0, eq[1]);
        float acc2 = __fmul_rn(A0, eq[2]), acc3 = __fmul_rn(A0, eq[3]);
        float acc4 = __fmul_rn(A0, eq[4]), acc5 = __fmul_rn(A0, eq[5]);
        float acc6 = __fmul_rn(A0, eq[6]), acc7 = __fmul_rn(A0, eq[7]);
#define STEP(c) { const float av = A##c; const float* er = eq + (c) * 8; \
        acc0 = __fmaf_rn(av, er[0], acc0); acc1 = __fmaf_rn(av, er[1], acc1); \
        acc2 = __fmaf_rn(av, er[2], acc2); acc3 = __fmaf_rn(av, er[3], acc3); \
        acc4 = __fmaf_rn(av, er[4], acc4); acc5 = __fmaf_rn(av, er[5], acc5); \
        acc6 = __fmaf_rn(av, er[6], acc6); acc7 = __fmaf_rn(av, er[7], acc7); }
        R63(STEP)
#undef STEP
        // distances, q ascending, strict <  (== t1 - fl(2*acc) bit-exact)
#define DIST(k) { float t1 = __fadd_rn(ffv, ees[k]); \
        float d = __fmaf_rn(acc##k, -2.0f, t1); \
        int q = qg * 8 + (k); \
        if (d < dmin) { dmin = d; kmin = q; } }
        DIST(0) DIST(1) DIST(2) DIST(3) DIST(4) DIST(5) DIST(6) DIST(7)
#undef DIST
    }

    // ---- indices out (as float)
    out[IDX_OFF + n] = (float)kmin;

    // ---- quantized out (straight-through) + loss partial
    double lacc = 0.0;
    {
        const float* eqr = emb + (long)kmin * 64;   // divergent, L2-hot, 16B-aligned
        float* op = out + (long)b * CDIM * THW + r;
#define EPI(c4, e0,e1,e2,e3) { \
        float4 ev = *(const float4*)(eqr + (c4) * 4); \
        float d0 = __fsub_rn(ev.x, A##e0); op[(long)(e0) * THW] = __fadd_rn(A##e0, d0); lacc += (double)__fmul_rn(d0, d0); \
        float d1 = __fsub_rn(ev.y, A##e1); op[(long)(e1) * THW] = __fadd_rn(A##e1, d1); lacc += (double)__fmul_rn(d1, d1); \
        float d2 = __fsub_rn(ev.z, A##e2); op[(long)(e2) * THW] = __fadd_rn(A##e2, d2); lacc += (double)__fmul_rn(d2, d2); \
        float d3 = __fsub_rn(ev.w, A##e3); op[(long)(e3) * THW] = __fadd_rn(A##e3, d3); lacc += (double)__fmul_rn(d3, d3); }
        EPI(0, 0,1,2,3)     EPI(1, 4,5,6,7)     EPI(2, 8,9,10,11)   EPI(3, 12,13,14,15)
        EPI(4, 16,17,18,19) EPI(5, 20,21,22,23) EPI(6, 24,25,26,27) EPI(7, 28,29,30,31)
        EPI(8, 32,33,34,35) EPI(9, 36,37,38,39) EPI(10,40,41,42,43) EPI(11,44,45,46,47)
        EPI(12,48,49,50,51) EPI(13,52,53,54,55) EPI(14,56,57,58,59) EPI(15,60,61,62,63)
#undef EPI
    }

    // ---- loss: wave reduce, then 4-wave LDS reduce, one atomic per block
    #pragma unroll
    for (int m = 1; m < 64; m <<= 1) lacc += __shfl_xor(lacc, m, 64);
    __shared__ double wsum[4];
    if ((tid & 63) == 0) wsum[tid >> 6] = lacc;
    __syncthreads();
    if (tid == 0) {
        atomicAdd(lossws, wsum[0] + wsum[1] + wsum[2] + wsum[3]);
    }
}

extern "C" __global__ void vq_finalize(const double* __restrict__ lossws,
                                       float* __restrict__ out) {
    if (threadIdx.x == 0) {
        float m = (float)(lossws[0] / (double)QOUT_N);
        out[LOSS_OFF] = __fadd_rn(m, __fmul_rn(0.025f, m));
    }
}

extern "C" void kernel_launch(void* const* d_in, const int* in_sizes, int n_in,
                              void* d_out, int out_size, void* d_ws, size_t ws_size,
                              hipStream_t stream) {
    const float* x   = (const float*)d_in[0];
    const float* emb = (const float*)d_in[1];
    float* out = (float*)d_out;
    double* loss_ws = (double*)d_ws;
    float* ee_ws  = (float*)((char*)d_ws + 256);
    float* etg_ws = (float*)((char*)d_ws + 4096);

    hipMemsetAsync(d_ws, 0, sizeof(double), stream);
    hipLaunchKernelGGL(vq_prep, dim3(1), dim3(KCODES), 0, stream, emb, ee_ws, etg_ws);

    dim3 grid(NPOS / NTHR);   // 2048
    dim3 block(NTHR);
    hipLaunchKernelGGL(vq_main, grid, block, 0, stream, x, emb, out, loss_ws, ee_ws, etg_ws);
    hipLaunchKernelGGL(vq_finalize, dim3(1), dim3(1), 0, stream,
                       (const double*)loss_ws, out);
}